// Round 7
// baseline (293.633 us; speedup 1.0000x reference)
//
#include <hip/hip_runtime.h>
#include <hip/hip_bf16.h>
#include <stdint.h>

// B=8, S=1024, NX=1024, H=16, D=64
typedef __bf16 bf16x8 __attribute__((ext_vector_type(8)));
typedef float  f32x4  __attribute__((ext_vector_type(4)));
typedef float  f32x16 __attribute__((ext_vector_type(16)));

#define BARRIER() asm volatile("s_barrier" ::: "memory")
#define VMCNT(n)  asm volatile("s_waitcnt vmcnt(" #n ")" ::: "memory")
#define LGKM0()   asm volatile("s_waitcnt lgkmcnt(0)" ::: "memory")
#define SCHED0()  __builtin_amdgcn_sched_barrier(0)

__device__ __forceinline__ void gload_lds16(const void* g, void* l) {
  __builtin_amdgcn_global_load_lds(
      (const __attribute__((address_space(1))) unsigned int*)g,
      (__attribute__((address_space(3))) unsigned int*)l, 16, 0, 0);
}

// ---------------- cast fp32 -> bf16, 4 elems/thread ----------------
__global__ void k_cast(const float* __restrict__ in, __bf16* __restrict__ out, int n4) {
  int i = blockIdx.x * blockDim.x + threadIdx.x;
  if (i >= n4) return;
  float4 v = reinterpret_cast<const float4*>(in)[i];
  union { __bf16 h[4]; uint64_t u; } c;
  c.h[0] = (__bf16)v.x; c.h[1] = (__bf16)v.y; c.h[2] = (__bf16)v.z; c.h[3] = (__bf16)v.w;
  *reinterpret_cast<uint64_t*>(out + 4l * i) = c.u;
}

// ------------- transpose fp32 [R][C] -> bf16 [C][R] ----------------
__global__ void k_transpose_cast(const float* __restrict__ in, __bf16* __restrict__ out,
                                 int R, int C) {
  __shared__ float t[32][33];
  const int tx = threadIdx.x & 31, ty = threadIdx.x >> 5;  // 32 x 8
  const int c0 = blockIdx.x * 32, r0 = blockIdx.y * 32;
#pragma unroll
  for (int rr = 0; rr < 4; ++rr)
    t[ty * 4 + rr][tx] = in[(long)(r0 + ty * 4 + rr) * C + c0 + tx];
  __syncthreads();
#pragma unroll
  for (int rr = 0; rr < 4; ++rr)
    out[(long)(c0 + ty * 4 + rr) * R + r0 + tx] = (__bf16)t[tx][ty * 4 + rr];
}

// ============ pipelined GEMM: C = A[M,K] * Bt[N,K]^T + bias ============
// Tile 256x128, BK=64, 8 waves (2m x 4n), per-wave C = 128x32 (acc[8][2]).
// LDS: 3 rotating buffers x {A 256x64 (32K), B 128x64 (16K)} = 144 KB.
// FINE-GRAINED: 4 phases per K-tile, each {<=6 ds_read_b128, 2 gload_lds,
// barrier, lgkmcnt(0), 8 MFMA, barrier}. Stage tile t+2 spread 2+2+2 over
// phases 0-2; vmcnt(6) once per K-tile at phase 3 (publishes tile t+1).
// Swizzle: byte-col ^= ((row&7)<<4) on gload source AND ds_read.
// MODE 0: scatter -> q[B,H,S,D] (pre-scaled 1/8), k[B,H,S,D], v^T[B,H,D,S]
// MODE 1: fp32 -> fo[M,N]
template <int MODE>
__launch_bounds__(512, 2)
__global__ void k_gemm_p(const __bf16* __restrict__ A, const __bf16* __restrict__ Bt,
                         const float* __restrict__ bias, int M, int N, int K, int NB,
                         __bf16* __restrict__ qo, __bf16* __restrict__ ko,
                         __bf16* __restrict__ vo, float* __restrict__ fo) {
  __shared__ __bf16 lds[3][24576];  // [buf][A: 0..16384 | B: 16384..24576]
  const int tid = threadIdx.x;
  const int l = tid & 63;
  const int w = tid >> 6;
  const int lm = l & 15, lq = l >> 4;
  const int wm = w >> 2, wn = w & 3;
  const int nwg = gridDim.x;
  const int wg = (blockIdx.x & 7) * (nwg >> 3) + (blockIdx.x >> 3);  // XCD swizzle (nwg%8==0)
  const int bm = wg / NB, bn = wg % NB;
  const int nt = K >> 6;

  // ---- staging addresses: thread covers row (tid>>3)+li*64, 16B at swizzled col ----
  const int rA = tid >> 3;
  const int scol = (((tid & 7) * 16) ^ ((rA & 7) << 4)) >> 1;  // element col (swizzled)
  long a_off[4], b_off[2];
#pragma unroll
  for (int li = 0; li < 4; ++li) a_off[li] = (long)(bm * 256 + li * 64 + rA) * K + scol;
#pragma unroll
  for (int li = 0; li < 2; ++li) b_off[li] = (long)(bn * 128 + li * 64 + rA) * K + scol;

#define STAGE_A01(buf, t) { \
    gload_lds16(A + a_off[0] + (long)(t) * 64, &lds[buf][tid * 8]); \
    gload_lds16(A + a_off[1] + (long)(t) * 64, &lds[buf][4096 + tid * 8]); }
#define STAGE_A23(buf, t) { \
    gload_lds16(A + a_off[2] + (long)(t) * 64, &lds[buf][8192 + tid * 8]); \
    gload_lds16(A + a_off[3] + (long)(t) * 64, &lds[buf][12288 + tid * 8]); }
#define STAGE_B01(buf, t) { \
    gload_lds16(Bt + b_off[0] + (long)(t) * 64, &lds[buf][16384 + tid * 8]); \
    gload_lds16(Bt + b_off[1] + (long)(t) * 64, &lds[buf][20480 + tid * 8]); }

  // ---- fragment read offsets (bytes within 128-B row, XOR-swizzled, ->elements) ----
  const int aswz = (lm & 7) << 4;
  const int cofs0 = ((0 * 64 + lq * 16) ^ aswz) >> 1;   // ks=0
  const int cofs1 = ((1 * 64 + lq * 16) ^ aswz) >> 1;   // ks=1
  const int arow = wm * 128 + lm;                        // + mi*16
  const int brow = wn * 32 + lm;                         // + nj*16

  f32x4 acc[8][2] = {};

  // ---- prologue: stage tiles 0,1 (12 loads); retire tile 0's 6 ----
  STAGE_A01(0, 0); STAGE_A23(0, 0); STAGE_B01(0, 0);
  STAGE_A01(1, 1); STAGE_A23(1, 1); STAGE_B01(1, 1);
  VMCNT(6); BARRIER();

  for (int t = 0; t < nt; ++t) {
    const __bf16* Lb = lds[t % 3];
    const int sb = (t + 2) % 3;
    const bool st = (t + 2 < nt);
    bf16x8 bf[2], af[4];

    // ===== phase 0: B ks0 + A mi0-3 ks0; stage A01(t+2); MFMA mi0-3 ks0 =====
    bf[0] = *(const bf16x8*)&Lb[16384 + (brow) * 64 + cofs0];
    bf[1] = *(const bf16x8*)&Lb[16384 + (brow + 16) * 64 + cofs0];
#pragma unroll
    for (int j = 0; j < 4; ++j)
      af[j] = *(const bf16x8*)&Lb[(arow + j * 16) * 64 + cofs0];
    if (st) STAGE_A01(sb, t + 2);
    BARRIER(); LGKM0(); SCHED0();
    __builtin_amdgcn_s_setprio(1);
#pragma unroll
    for (int j = 0; j < 4; ++j)
#pragma unroll
      for (int nj = 0; nj < 2; ++nj)
        acc[j][nj] = __builtin_amdgcn_mfma_f32_16x16x32_bf16(af[j], bf[nj], acc[j][nj], 0, 0, 0);
    __builtin_amdgcn_s_setprio(0);
    SCHED0(); BARRIER();

    // ===== phase 1: A mi4-7 ks0; stage A23(t+2); MFMA mi4-7 ks0 (bf kept) =====
#pragma unroll
    for (int j = 0; j < 4; ++j)
      af[j] = *(const bf16x8*)&Lb[(arow + (j + 4) * 16) * 64 + cofs0];
    if (st) STAGE_A23(sb, t + 2);
    BARRIER(); LGKM0(); SCHED0();
    __builtin_amdgcn_s_setprio(1);
#pragma unroll
    for (int j = 0; j < 4; ++j)
#pragma unroll
      for (int nj = 0; nj < 2; ++nj)
        acc[j + 4][nj] = __builtin_amdgcn_mfma_f32_16x16x32_bf16(af[j], bf[nj], acc[j + 4][nj], 0, 0, 0);
    __builtin_amdgcn_s_setprio(0);
    SCHED0(); BARRIER();

    // ===== phase 2: B ks1 + A mi0-3 ks1; stage B01(t+2); MFMA mi0-3 ks1 =====
    bf[0] = *(const bf16x8*)&Lb[16384 + (brow) * 64 + cofs1];
    bf[1] = *(const bf16x8*)&Lb[16384 + (brow + 16) * 64 + cofs1];
#pragma unroll
    for (int j = 0; j < 4; ++j)
      af[j] = *(const bf16x8*)&Lb[(arow + j * 16) * 64 + cofs1];
    if (st) STAGE_B01(sb, t + 2);
    BARRIER(); LGKM0(); SCHED0();
    __builtin_amdgcn_s_setprio(1);
#pragma unroll
    for (int j = 0; j < 4; ++j)
#pragma unroll
      for (int nj = 0; nj < 2; ++nj)
        acc[j][nj] = __builtin_amdgcn_mfma_f32_16x16x32_bf16(af[j], bf[nj], acc[j][nj], 0, 0, 0);
    __builtin_amdgcn_s_setprio(0);
    SCHED0(); BARRIER();

    // ===== phase 3: A mi4-7 ks1; vmcnt(6) publishes tile t+1; MFMA mi4-7 ks1 =====
#pragma unroll
    for (int j = 0; j < 4; ++j)
      af[j] = *(const bf16x8*)&Lb[(arow + (j + 4) * 16) * 64 + cofs1];
    if (st) { VMCNT(6); }
    else if (t + 1 < nt) { VMCNT(0); }
    BARRIER(); LGKM0(); SCHED0();
    __builtin_amdgcn_s_setprio(1);
#pragma unroll
    for (int j = 0; j < 4; ++j)
#pragma unroll
      for (int nj = 0; nj < 2; ++nj)
        acc[j + 4][nj] = __builtin_amdgcn_mfma_f32_16x16x32_bf16(af[j], bf[nj], acc[j + 4][nj], 0, 0, 0);
    __builtin_amdgcn_s_setprio(0);
    SCHED0(); BARRIER();
  }

  // ---- epilogue ----
  if (MODE == 0) {
#pragma unroll
    for (int nj = 0; nj < 2; ++nj) {
      const int c = bn * 128 + wn * 32 + nj * 16 + lm;
      const float bv = bias[c];
      const int which = c >> 10, cc = c & 1023, hh = cc >> 6, d = cc & 63;
#pragma unroll
      for (int mi = 0; mi < 8; ++mi)
#pragma unroll
        for (int i = 0; i < 4; ++i) {
          const int r = bm * 256 + wm * 128 + mi * 16 + lq * 4 + i;
          const int b = r >> 10, s_ = r & 1023;
          float fv = acc[mi][nj][i] + bv;
          if (which == 0) fv *= 0.125f;  // fold 1/sqrt(D) into Q
          const __bf16 v = (__bf16)fv;
          const long hb = (long)(b * 16 + hh);
          if (which == 0)      qo[(hb * 1024 + s_) * 64 + d] = v;
          else if (which == 1) ko[(hb * 1024 + s_) * 64 + d] = v;
          else                 vo[(hb * 64 + d) * 1024 + s_] = v;
        }
    }
  } else {
#pragma unroll
    for (int nj = 0; nj < 2; ++nj) {
      const int c = bn * 128 + wn * 32 + nj * 16 + lm;
      const float bv = bias[c];
#pragma unroll
      for (int mi = 0; mi < 8; ++mi)
#pragma unroll
        for (int i = 0; i < 4; ++i) {
          const int r = bm * 256 + wm * 128 + mi * 16 + lq * 4 + i;
          fo[(long)r * N + c] = acc[mi][nj][i] + bv;
        }
    }
  }
#undef STAGE_A01
#undef STAGE_A23
#undef STAGE_B01
}

// ---------------- causal flash attention, 32x32 swapped-QK^T, no LDS ----------------
__device__ __forceinline__ void attn_qtile(const __bf16* __restrict__ Q,
                                           const __bf16* __restrict__ Kh,
                                           const __bf16* __restrict__ Vt,
                                           __bf16* __restrict__ ob,
                                           int b, int h, int qbw, int l) {
  const int lm = l & 31, hi = l >> 5;

  bf16x8 qf[4];
#pragma unroll
  for (int ds = 0; ds < 4; ++ds)
    qf[ds] = *(const bf16x8*)(Q + (long)(qbw + lm) * 64 + ds * 16 + hi * 8);

  f32x16 oacc0 = {}, oacc1 = {};
  float m = -__builtin_inff(), s = 0.f;

  const int ntiles = (qbw >> 5) + 1;
  for (int kt = 0; kt < ntiles; ++kt) {
    const int k0 = kt * 32;
    f32x16 st = {};
#pragma unroll
    for (int ds = 0; ds < 4; ++ds) {
      bf16x8 kf = *(const bf16x8*)(Kh + (long)(k0 + lm) * 64 + ds * 16 + hi * 8);
      st = __builtin_amdgcn_mfma_f32_32x32x16_bf16(kf, qf[ds], st, 0, 0, 0);
    }
    if (kt == ntiles - 1) {
      const int q = qbw + lm;
#pragma unroll
      for (int r = 0; r < 16; ++r) {
        const int key = k0 + (r & 3) + 8 * (r >> 2) + 4 * hi;
        if (key > q) st[r] = -__builtin_inff();
      }
    }
    float tm = st[0];
#pragma unroll
    for (int r = 1; r < 16; ++r) tm = fmaxf(tm, st[r]);
    tm = fmaxf(tm, __shfl_xor(tm, 32));
    if (!__all(tm <= m + 8.f)) {   // defer-max
      const float mn = fmaxf(m, tm);
      const float fac = __expf(m - mn);
      m = mn;
      s *= fac;
#pragma unroll
      for (int r = 0; r < 16; ++r) {
        const int qr = (r & 3) + 8 * (r >> 2) + 4 * hi;
        const float fr = __int_as_float(
            __builtin_amdgcn_ds_bpermute(qr * 4, __float_as_int(fac)));
        oacc0[r] *= fr; oacc1[r] *= fr;
      }
    }
    float p[16], ts = 0.f;
#pragma unroll
    for (int r = 0; r < 16; ++r) { p[r] = __expf(st[r] - m); ts += p[r]; }
    ts += __shfl_xor(ts, 32);
    s += ts;
    unsigned int w8[8];
#pragma unroll
    for (int t = 0; t < 8; ++t) {
      union { __bf16 hh[2]; unsigned int u; } pk;
      pk.hh[0] = (__bf16)p[2 * t]; pk.hh[1] = (__bf16)p[2 * t + 1];
      w8[t] = pk.u;
    }
    const unsigned int e0 = __shfl_xor(hi ? w8[0] : w8[2], 32);
    const unsigned int e1 = __shfl_xor(hi ? w8[1] : w8[3], 32);
    const unsigned int e2 = __shfl_xor(hi ? w8[4] : w8[6], 32);
    const unsigned int e3 = __shfl_xor(hi ? w8[5] : w8[7], 32);
    union { unsigned int wd[4]; bf16x8 v; } pa0, pa1;
    if (hi) {
      pa0.wd[0] = e0;    pa0.wd[1] = e1;    pa0.wd[2] = w8[2]; pa0.wd[3] = w8[3];
      pa1.wd[0] = e2;    pa1.wd[1] = e3;    pa1.wd[2] = w8[6]; pa1.wd[3] = w8[7];
    } else {
      pa0.wd[0] = w8[0]; pa0.wd[1] = w8[1]; pa0.wd[2] = e0;    pa0.wd[3] = e1;
      pa1.wd[0] = w8[4]; pa1.wd[1] = w8[5]; pa1.wd[2] = e2;    pa1.wd[3] = e3;
    }
#pragma unroll
    for (int t = 0; t < 2; ++t) {
      const bf16x8 pa = t ? pa1.v : pa0.v;
      bf16x8 vf0 = *(const bf16x8*)(Vt + (long)lm * 1024 + k0 + t * 16 + hi * 8);
      bf16x8 vf1 = *(const bf16x8*)(Vt + (long)(32 + lm) * 1024 + k0 + t * 16 + hi * 8);
      oacc0 = __builtin_amdgcn_mfma_f32_32x32x16_bf16(pa, vf0, oacc0, 0, 0, 0);
      oacc1 = __builtin_amdgcn_mfma_f32_32x32x16_bf16(pa, vf1, oacc1, 0, 0, 0);
    }
  }
  const float invs = 1.f / s;
#pragma unroll
  for (int r = 0; r < 16; ++r) {
    const int qr = (r & 3) + 8 * (r >> 2) + 4 * hi;
    const float inv = __int_as_float(
        __builtin_amdgcn_ds_bpermute(qr * 4, __float_as_int(invs)));
    const long row = (long)(b * 1024 + qbw + qr) * 1024 + h * 64;
    ob[row + lm]      = (__bf16)(oacc0[r] * inv);
    ob[row + 32 + lm] = (__bf16)(oacc1[r] * inv);
  }
}

// 512 blocks, XCD-affinity mapping: the 4 blocks of one (b,h) get ids congruent
// mod 8 -> same XCD -> K/V panel (256 KB) stays in that XCD's L2.
__global__ void k_attn(const __bf16* __restrict__ qb_, const __bf16* __restrict__ kb,
                       const __bf16* __restrict__ vtb, __bf16* __restrict__ ob) {
  const int l = threadIdx.x & 63, w = threadIdx.x >> 6;
  const int bid = blockIdx.x;
  const int xcd = bid & 7, slot = bid >> 3;      // slot 0..63
  const int bh = xcd + 8 * (slot >> 2);          // 16 bh-groups per XCD
  const int j = slot & 3;
  const int wi = j * 4 + w;                      // 0..15
  const int b = bh >> 4, h = bh & 15;
  const __bf16* Q  = qb_ + (long)bh * 65536;
  const __bf16* Kh = kb  + (long)bh * 65536;
  const __bf16* Vt = vtb + (long)bh * 65536;
  attn_qtile(Q, Kh, Vt, ob, b, h, wi * 32, l);
  attn_qtile(Q, Kh, Vt, ob, b, h, (31 - wi) * 32, l);
}

extern "C" void kernel_launch(void* const* d_in, const int* in_sizes, int n_in,
                              void* d_out, int out_size, void* d_ws, size_t ws_size,
                              hipStream_t stream) {
  const float* x      = (const float*)d_in[0];
  const float* w_attn = (const float*)d_in[1];
  const float* b_attn = (const float*)d_in[2];
  const float* w_proj = (const float*)d_in[3];
  const float* b_proj = (const float*)d_in[4];
  float* out = (float*)d_out;

  char* ws = (char*)d_ws;
  const size_t SZ_XBF = (size_t)8192 * 1024 * 2;   // 16.8 MB
  __bf16* x_bf = (__bf16*)ws;  ws += SZ_XBF;
  __bf16* wat  = (__bf16*)ws;  ws += (size_t)3072 * 1024 * 2;
  __bf16* wpt  = (__bf16*)ws;  ws += (size_t)1024 * 1024 * 2;
  __bf16* qb   = (__bf16*)ws;  ws += SZ_XBF;       // [B,H,S,D], pre-scaled 1/8
  __bf16* kb   = (__bf16*)ws;  ws += SZ_XBF;       // [B,H,S,D]
  __bf16* vtb  = (__bf16*)ws;  ws += SZ_XBF;       // [B,H,D,S]
  __bf16* obf  = (__bf16*)ws;  ws += SZ_XBF;       // [B,S,NX]

  k_cast<<<8192, 256, 0, stream>>>(x, x_bf, 2097152);
  k_transpose_cast<<<dim3(96, 32), 256, 0, stream>>>(w_attn, wat, 1024, 3072);
  k_transpose_cast<<<dim3(32, 32), 256, 0, stream>>>(w_proj, wpt, 1024, 1024);
  // QKV: M=8192, N=3072 -> 32x24 = 768 blocks (3 exact CU rounds)
  k_gemm_p<0><<<768, 512, 0, stream>>>(x_bf, wat, b_attn, 8192, 3072, 1024, 24,
                                       qb, kb, vtb, nullptr);
  k_attn<<<512, 256, 0, stream>>>(qb, kb, vtb, obf);
  // proj: M=8192, N=1024 -> 32x8 = 256 blocks (1 exact CU round)
  k_gemm_p<1><<<256, 512, 0, stream>>>(obf, wpt, b_proj, 8192, 1024, 1024, 8,
                                       nullptr, nullptr, nullptr, out);
}

// Round 8
// 285.890 us; speedup vs baseline: 1.0271x; 1.0271x over previous
//
#include <hip/hip_runtime.h>
#include <hip/hip_bf16.h>
#include <stdint.h>

// B=8, S=1024, NX=1024, H=16, D=64
typedef __bf16 bf16x8 __attribute__((ext_vector_type(8)));
typedef float  f32x4  __attribute__((ext_vector_type(4)));
typedef float  f32x16 __attribute__((ext_vector_type(16)));

#define BARRIER() asm volatile("s_barrier" ::: "memory")
#define VMCNT(n)  asm volatile("s_waitcnt vmcnt(" #n ")" ::: "memory")
#define LGKM0()   asm volatile("s_waitcnt lgkmcnt(0)" ::: "memory")
#define SCHED0()  __builtin_amdgcn_sched_barrier(0)

__device__ __forceinline__ void gload_lds16(const void* g, void* l) {
  __builtin_amdgcn_global_load_lds(
      (const __attribute__((address_space(1))) unsigned int*)g,
      (__attribute__((address_space(3))) unsigned int*)l, 16, 0, 0);
}

// ---------------- cast fp32 -> bf16, 4 elems/thread ----------------
__global__ void k_cast(const float* __restrict__ in, __bf16* __restrict__ out, int n4) {
  int i = blockIdx.x * blockDim.x + threadIdx.x;
  if (i >= n4) return;
  float4 v = reinterpret_cast<const float4*>(in)[i];
  union { __bf16 h[4]; uint64_t u; } c;
  c.h[0] = (__bf16)v.x; c.h[1] = (__bf16)v.y; c.h[2] = (__bf16)v.z; c.h[3] = (__bf16)v.w;
  *reinterpret_cast<uint64_t*>(out + 4l * i) = c.u;
}

// ------------- transpose fp32 [R][C] -> bf16 [C][R] ----------------
__global__ void k_transpose_cast(const float* __restrict__ in, __bf16* __restrict__ out,
                                 int R, int C) {
  __shared__ float t[32][33];
  const int tx = threadIdx.x & 31, ty = threadIdx.x >> 5;  // 32 x 8
  const int c0 = blockIdx.x * 32, r0 = blockIdx.y * 32;
#pragma unroll
  for (int rr = 0; rr < 4; ++rr)
    t[ty * 4 + rr][tx] = in[(long)(r0 + ty * 4 + rr) * C + c0 + tx];
  __syncthreads();
#pragma unroll
  for (int rr = 0; rr < 4; ++rr)
    out[(long)(c0 + ty * 4 + rr) * R + r0 + tx] = (__bf16)t[tx][ty * 4 + rr];
}

// ============ GEMM: C = A[M,K] * Bt[N,K]^T + bias ============
// Tile 128x128, BK=64, 4 waves (2m x 2n), per-wave C = 64x64 (acc[4][4]).
// LDS: 2 buffers x {A 128x64 (16K) + B 128x64 (16K)} = 64 KB -> 2 blocks/CU
// (independent barrier domains = inter-block latency hiding, m114).
// Per K-tile: stage next tile (8 gloads), VMCNT(8) counted, 2 barriers, 32 MFMA.
// Swizzle: byte-col ^= ((row&7)<<4) on gload source AND ds_read.
// XCD mapping: each XCD owns an N-slice (B panel L2-resident).
// MODE 0: scatter -> q[B,H,S,D] (pre-scaled 1/8), k[B,H,S,D], v^T[B,H,D,S]
// MODE 1: fp32 -> fo[M,N]
template <int MODE>
__launch_bounds__(256, 2)
__global__ void k_gemm2(const __bf16* __restrict__ A, const __bf16* __restrict__ Bt,
                        const float* __restrict__ bias, int M, int N, int K, int NBX,
                        __bf16* __restrict__ qo, __bf16* __restrict__ ko,
                        __bf16* __restrict__ vo, float* __restrict__ fo) {
  __shared__ __bf16 lds[2][2][8192];  // [buf][A/B][128 rows x 64 cols]
  const int tid = threadIdx.x;
  const int l = tid & 63, w = tid >> 6;          // 4 waves
  const int lm = l & 15, lq = l >> 4;
  const int wm = w >> 1, wn = w & 1;
  // XCD-affinity: xcd owns bn in [xcd*NBX, (xcd+1)*NBX)
  const int xcd = blockIdx.x & 7, s = blockIdx.x >> 3;
  const int bn = xcd * NBX + s % NBX;
  const int bm = s / NBX;
  const int nt = K >> 6;

  // staging: thread covers row (li*32 + tid>>3), 16B chunk (tid&7), pre-swizzled src
  const int rA = tid >> 3;
  const int scol = (((tid & 7) * 16) ^ ((rA & 7) << 4)) >> 1;  // elements
  long a_off[4], b_off[4];
#pragma unroll
  for (int li = 0; li < 4; ++li) {
    a_off[li] = (long)(bm * 128 + li * 32 + rA) * K + scol;
    b_off[li] = (long)(bn * 128 + li * 32 + rA) * K + scol;
  }
#define STAGE(buf, t) { \
    gload_lds16(A + a_off[0] + (long)(t) * 64, &lds[buf][0][tid * 8]); \
    gload_lds16(A + a_off[1] + (long)(t) * 64, &lds[buf][0][2048 + tid * 8]); \
    gload_lds16(A + a_off[2] + (long)(t) * 64, &lds[buf][0][4096 + tid * 8]); \
    gload_lds16(A + a_off[3] + (long)(t) * 64, &lds[buf][0][6144 + tid * 8]); \
    gload_lds16(Bt + b_off[0] + (long)(t) * 64, &lds[buf][1][tid * 8]); \
    gload_lds16(Bt + b_off[1] + (long)(t) * 64, &lds[buf][1][2048 + tid * 8]); \
    gload_lds16(Bt + b_off[2] + (long)(t) * 64, &lds[buf][1][4096 + tid * 8]); \
    gload_lds16(Bt + b_off[3] + (long)(t) * 64, &lds[buf][1][6144 + tid * 8]); }

  // fragment read offsets (element units; row stride 64 elems = 128 B)
  const int aswz = (lm & 7) << 4;
  const int cofs0 = ((0 * 64 + lq * 16) ^ aswz) >> 1;
  const int cofs1 = ((1 * 64 + lq * 16) ^ aswz) >> 1;
  const int arow = wm * 64 + lm;   // + mi*16
  const int brow = wn * 64 + lm;   // + ni*16

  f32x4 acc[4][4] = {};

  STAGE(0, 0);  // prologue: tile 0 in flight (8)

  for (int t = 0; t < nt; ++t) {
    const int cur = t & 1;
    if (t + 1 < nt) { STAGE(cur ^ 1, t + 1); VMCNT(8); }
    else VMCNT(0);
    BARRIER();
    const __bf16* La = lds[cur][0];
    const __bf16* Lbv = lds[cur][1];
    bf16x8 af[4][2], bfr[4][2];
#pragma unroll
    for (int mi = 0; mi < 4; ++mi) {
      af[mi][0] = *(const bf16x8*)&La[(arow + mi * 16) * 64 + cofs0];
      af[mi][1] = *(const bf16x8*)&La[(arow + mi * 16) * 64 + cofs1];
    }
#pragma unroll
    for (int ni = 0; ni < 4; ++ni) {
      bfr[ni][0] = *(const bf16x8*)&Lbv[(brow + ni * 16) * 64 + cofs0];
      bfr[ni][1] = *(const bf16x8*)&Lbv[(brow + ni * 16) * 64 + cofs1];
    }
    LGKM0(); SCHED0();
    __builtin_amdgcn_s_setprio(1);
#pragma unroll
    for (int ks = 0; ks < 2; ++ks)
#pragma unroll
      for (int mi = 0; mi < 4; ++mi)
#pragma unroll
        for (int ni = 0; ni < 4; ++ni)
          acc[mi][ni] = __builtin_amdgcn_mfma_f32_16x16x32_bf16(af[mi][ks], bfr[ni][ks],
                                                                acc[mi][ni], 0, 0, 0);
    __builtin_amdgcn_s_setprio(0);
    SCHED0();
    BARRIER();  // reads done before next iter's STAGE overwrites buf^1
  }

  if (MODE == 0) {
#pragma unroll
    for (int ni = 0; ni < 4; ++ni) {
      const int c = bn * 128 + wn * 64 + ni * 16 + lm;
      const float bv = bias[c];
      const int which = c >> 10, cc = c & 1023, hh = cc >> 6, d = cc & 63;
#pragma unroll
      for (int mi = 0; mi < 4; ++mi)
#pragma unroll
        for (int i = 0; i < 4; ++i) {
          const int r = bm * 128 + wm * 64 + mi * 16 + lq * 4 + i;
          const int b = r >> 10, s_ = r & 1023;
          float fv = acc[mi][ni][i] + bv;
          if (which == 0) fv *= 0.125f;  // fold 1/sqrt(D) into Q
          const __bf16 v = (__bf16)fv;
          const long hb = (long)(b * 16 + hh);
          if (which == 0)      qo[(hb * 1024 + s_) * 64 + d] = v;
          else if (which == 1) ko[(hb * 1024 + s_) * 64 + d] = v;
          else                 vo[(hb * 64 + d) * 1024 + s_] = v;
        }
    }
  } else {
#pragma unroll
    for (int ni = 0; ni < 4; ++ni) {
      const int c = bn * 128 + wn * 64 + ni * 16 + lm;
      const float bv = bias[c];
#pragma unroll
      for (int mi = 0; mi < 4; ++mi)
#pragma unroll
        for (int i = 0; i < 4; ++i) {
          const int r = bm * 128 + wm * 64 + mi * 16 + lq * 4 + i;
          fo[(long)r * N + c] = acc[mi][ni][i] + bv;
        }
    }
  }
#undef STAGE
}

// -------- causal flash attention, KVBLK=64, swapped-QK^T, no LDS --------
// Per iter: 2 independent QK chains (8 MFMA, ILP), ONE softmax/rescale/pack
// pass over 64 keys, 8 PV MFMA. Halves serial-softmax passes vs KVBLK=32.
__device__ __forceinline__ void attn_qtile(const __bf16* __restrict__ Q,
                                           const __bf16* __restrict__ Kh,
                                           const __bf16* __restrict__ Vt,
                                           __bf16* __restrict__ ob,
                                           int b, int h, int qbw, int l) {
  const int lm = l & 31, hi = l >> 5;

  bf16x8 qf[4];
#pragma unroll
  for (int ds = 0; ds < 4; ++ds)
    qf[ds] = *(const bf16x8*)(Q + (long)(qbw + lm) * 64 + ds * 16 + hi * 8);

  f32x16 oacc0 = {}, oacc1 = {};
  float m = -__builtin_inff(), s = 0.f;

  const int nt64 = (qbw >> 6) + 1;  // 64-key blocks; last may be part-masked
  for (int kt = 0; kt < nt64; ++kt) {
    const int k0 = kt * 64;
    f32x16 st0 = {}, st1 = {};
#pragma unroll
    for (int ds = 0; ds < 4; ++ds) {
      bf16x8 kf0 = *(const bf16x8*)(Kh + (long)(k0 + lm) * 64 + ds * 16 + hi * 8);
      bf16x8 kf1 = *(const bf16x8*)(Kh + (long)(k0 + 32 + lm) * 64 + ds * 16 + hi * 8);
      st0 = __builtin_amdgcn_mfma_f32_32x32x16_bf16(kf0, qf[ds], st0, 0, 0, 0);
      st1 = __builtin_amdgcn_mfma_f32_32x32x16_bf16(kf1, qf[ds], st1, 0, 0, 0);
    }
    if (kt == nt64 - 1) {  // diagonal / tail masking
      const int q = qbw + lm;
#pragma unroll
      for (int r = 0; r < 16; ++r) {
        const int key = k0 + (r & 3) + 8 * (r >> 2) + 4 * hi;
        if (key > q)      st0[r] = -__builtin_inff();
        if (key + 32 > q) st1[r] = -__builtin_inff();
      }
    }
    float tm = fmaxf(st0[0], st1[0]);
#pragma unroll
    for (int r = 1; r < 16; ++r) tm = fmaxf(tm, fmaxf(st0[r], st1[r]));
    tm = fmaxf(tm, __shfl_xor(tm, 32));
    if (!__all(tm <= m + 8.f)) {   // defer-max
      const float mn = fmaxf(m, tm);
      const float fac = __expf(m - mn);
      m = mn;
      s *= fac;
#pragma unroll
      for (int r = 0; r < 16; ++r) {
        const int qr = (r & 3) + 8 * (r >> 2) + 4 * hi;
        const float fr = __int_as_float(
            __builtin_amdgcn_ds_bpermute(qr * 4, __float_as_int(fac)));
        oacc0[r] *= fr; oacc1[r] *= fr;
      }
    }
    float ts = 0.f;
    unsigned int w8a[8], w8b[8];
#pragma unroll
    for (int t = 0; t < 8; ++t) {
      const float pa_ = __expf(st0[2 * t] - m), pb_ = __expf(st0[2 * t + 1] - m);
      ts += pa_ + pb_;
      union { __bf16 hh[2]; unsigned int u; } pk;
      pk.hh[0] = (__bf16)pa_; pk.hh[1] = (__bf16)pb_;
      w8a[t] = pk.u;
    }
#pragma unroll
    for (int t = 0; t < 8; ++t) {
      const float pa_ = __expf(st1[2 * t] - m), pb_ = __expf(st1[2 * t + 1] - m);
      ts += pa_ + pb_;
      union { __bf16 hh[2]; unsigned int u; } pk;
      pk.hh[0] = (__bf16)pa_; pk.hh[1] = (__bf16)pb_;
      w8b[t] = pk.u;
    }
    ts += __shfl_xor(ts, 32);
    s += ts;
    // build 4 PV A-frags: pa0/pa1 from w8a (keys k0+0..31), pa2/pa3 from w8b
    union { unsigned int wd[4]; bf16x8 v; } pa[4];
    {
      const unsigned int e0 = __shfl_xor(hi ? w8a[0] : w8a[2], 32);
      const unsigned int e1 = __shfl_xor(hi ? w8a[1] : w8a[3], 32);
      const unsigned int e2 = __shfl_xor(hi ? w8a[4] : w8a[6], 32);
      const unsigned int e3 = __shfl_xor(hi ? w8a[5] : w8a[7], 32);
      if (hi) {
        pa[0].wd[0] = e0;     pa[0].wd[1] = e1;     pa[0].wd[2] = w8a[2]; pa[0].wd[3] = w8a[3];
        pa[1].wd[0] = e2;     pa[1].wd[1] = e3;     pa[1].wd[2] = w8a[6]; pa[1].wd[3] = w8a[7];
      } else {
        pa[0].wd[0] = w8a[0]; pa[0].wd[1] = w8a[1]; pa[0].wd[2] = e0;     pa[0].wd[3] = e1;
        pa[1].wd[0] = w8a[4]; pa[1].wd[1] = w8a[5]; pa[1].wd[2] = e2;     pa[1].wd[3] = e3;
      }
    }
    {
      const unsigned int e0 = __shfl_xor(hi ? w8b[0] : w8b[2], 32);
      const unsigned int e1 = __shfl_xor(hi ? w8b[1] : w8b[3], 32);
      const unsigned int e2 = __shfl_xor(hi ? w8b[4] : w8b[6], 32);
      const unsigned int e3 = __shfl_xor(hi ? w8b[5] : w8b[7], 32);
      if (hi) {
        pa[2].wd[0] = e0;     pa[2].wd[1] = e1;     pa[2].wd[2] = w8b[2]; pa[2].wd[3] = w8b[3];
        pa[3].wd[0] = e2;     pa[3].wd[1] = e3;     pa[3].wd[2] = w8b[6]; pa[3].wd[3] = w8b[7];
      } else {
        pa[2].wd[0] = w8b[0]; pa[2].wd[1] = w8b[1]; pa[2].wd[2] = e0;     pa[2].wd[3] = e1;
        pa[3].wd[0] = w8b[4]; pa[3].wd[1] = w8b[5]; pa[3].wd[2] = e2;     pa[3].wd[3] = e3;
      }
    }
#pragma unroll
    for (int t = 0; t < 4; ++t) {
      bf16x8 vf0 = *(const bf16x8*)(Vt + (long)lm * 1024 + k0 + t * 16 + hi * 8);
      bf16x8 vf1 = *(const bf16x8*)(Vt + (long)(32 + lm) * 1024 + k0 + t * 16 + hi * 8);
      oacc0 = __builtin_amdgcn_mfma_f32_32x32x16_bf16(pa[t].v, vf0, oacc0, 0, 0, 0);
      oacc1 = __builtin_amdgcn_mfma_f32_32x32x16_bf16(pa[t].v, vf1, oacc1, 0, 0, 0);
    }
  }
  const float invs = 1.f / s;
#pragma unroll
  for (int r = 0; r < 16; ++r) {
    const int qr = (r & 3) + 8 * (r >> 2) + 4 * hi;
    const float inv = __int_as_float(
        __builtin_amdgcn_ds_bpermute(qr * 4, __float_as_int(invs)));
    const long row = (long)(b * 1024 + qbw + qr) * 1024 + h * 64;
    ob[row + lm]      = (__bf16)(oacc0[r] * inv);
    ob[row + 32 + lm] = (__bf16)(oacc1[r] * inv);
  }
}

// 512 blocks, XCD-affinity: the 4 blocks of one (b,h) land on one XCD.
__global__ void k_attn(const __bf16* __restrict__ qb_, const __bf16* __restrict__ kb,
                       const __bf16* __restrict__ vtb, __bf16* __restrict__ ob) {
  const int l = threadIdx.x & 63, w = threadIdx.x >> 6;
  const int bid = blockIdx.x;
  const int xcd = bid & 7, slot = bid >> 3;
  const int bh = xcd + 8 * (slot >> 2);
  const int j = slot & 3;
  const int wi = j * 4 + w;                      // 0..15
  const int b = bh >> 4, h = bh & 15;
  const __bf16* Q  = qb_ + (long)bh * 65536;
  const __bf16* Kh = kb  + (long)bh * 65536;
  const __bf16* Vt = vtb + (long)bh * 65536;
  attn_qtile(Q, Kh, Vt, ob, b, h, wi * 32, l);         // wi & 31-wi have opposite
  attn_qtile(Q, Kh, Vt, ob, b, h, (31 - wi) * 32, l);  // parity: balanced waste
}

extern "C" void kernel_launch(void* const* d_in, const int* in_sizes, int n_in,
                              void* d_out, int out_size, void* d_ws, size_t ws_size,
                              hipStream_t stream) {
  const float* x      = (const float*)d_in[0];
  const float* w_attn = (const float*)d_in[1];
  const float* b_attn = (const float*)d_in[2];
  const float* w_proj = (const float*)d_in[3];
  const float* b_proj = (const float*)d_in[4];
  float* out = (float*)d_out;

  char* ws = (char*)d_ws;
  const size_t SZ_XBF = (size_t)8192 * 1024 * 2;   // 16.8 MB
  __bf16* x_bf = (__bf16*)ws;  ws += SZ_XBF;
  __bf16* wat  = (__bf16*)ws;  ws += (size_t)3072 * 1024 * 2;
  __bf16* wpt  = (__bf16*)ws;  ws += (size_t)1024 * 1024 * 2;
  __bf16* qb   = (__bf16*)ws;  ws += SZ_XBF;       // [B,H,S,D], pre-scaled 1/8
  __bf16* kb   = (__bf16*)ws;  ws += SZ_XBF;       // [B,H,S,D]
  __bf16* vtb  = (__bf16*)ws;  ws += SZ_XBF;       // [B,H,D,S]
  __bf16* obf  = (__bf16*)ws;  ws += SZ_XBF;       // [B,S,NX]

  k_cast<<<8192, 256, 0, stream>>>(x, x_bf, 2097152);
  k_transpose_cast<<<dim3(96, 32), 256, 0, stream>>>(w_attn, wat, 1024, 3072);
  k_transpose_cast<<<dim3(32, 32), 256, 0, stream>>>(w_proj, wpt, 1024, 1024);
  // QKV: M=8192 (64 bm) x N=3072 (24 bn) -> 1536 blocks; NBX = 24/8 = 3
  k_gemm2<0><<<1536, 256, 0, stream>>>(x_bf, wat, b_attn, 8192, 3072, 1024, 3,
                                       qb, kb, vtb, nullptr);
  k_attn<<<512, 256, 0, stream>>>(qb, kb, vtb, obf);
  // proj: 64 bm x 8 bn -> 512 blocks; NBX = 1
  k_gemm2<1><<<512, 256, 0, stream>>>(obf, wpt, b_proj, 8192, 1024, 1024, 1,
                                      nullptr, nullptr, nullptr, out);
}

// Round 9
// 278.814 us; speedup vs baseline: 1.0531x; 1.0254x over previous
//
#include <hip/hip_runtime.h>
#include <hip/hip_bf16.h>
#include <stdint.h>

// B=8, S=1024, NX=1024, H=16, D=64
typedef __bf16 bf16x8 __attribute__((ext_vector_type(8)));
typedef float  f32x4  __attribute__((ext_vector_type(4)));
typedef float  f32x16 __attribute__((ext_vector_type(16)));

#define BARRIER() asm volatile("s_barrier" ::: "memory")
#define VMCNT(n)  asm volatile("s_waitcnt vmcnt(" #n ")" ::: "memory")
#define LGKM0()   asm volatile("s_waitcnt lgkmcnt(0)" ::: "memory")
#define SCHED0()  __builtin_amdgcn_sched_barrier(0)

__device__ __forceinline__ void gload_lds16(const void* g, void* l) {
  __builtin_amdgcn_global_load_lds(
      (const __attribute__((address_space(1))) unsigned int*)g,
      (__attribute__((address_space(3))) unsigned int*)l, 16, 0, 0);
}

// ---------------- cast fp32 -> bf16, 4 elems/thread ----------------
__global__ void k_cast(const float* __restrict__ in, __bf16* __restrict__ out, int n4) {
  int i = blockIdx.x * blockDim.x + threadIdx.x;
  if (i >= n4) return;
  float4 v = reinterpret_cast<const float4*>(in)[i];
  union { __bf16 h[4]; uint64_t u; } c;
  c.h[0] = (__bf16)v.x; c.h[1] = (__bf16)v.y; c.h[2] = (__bf16)v.z; c.h[3] = (__bf16)v.w;
  *reinterpret_cast<uint64_t*>(out + 4l * i) = c.u;
}

// ------------- transpose fp32 [R][C] -> bf16 [C][R] ----------------
__global__ void k_transpose_cast(const float* __restrict__ in, __bf16* __restrict__ out,
                                 int R, int C) {
  __shared__ float t[32][33];
  const int tx = threadIdx.x & 31, ty = threadIdx.x >> 5;  // 32 x 8
  const int c0 = blockIdx.x * 32, r0 = blockIdx.y * 32;
#pragma unroll
  for (int rr = 0; rr < 4; ++rr)
    t[ty * 4 + rr][tx] = in[(long)(r0 + ty * 4 + rr) * C + c0 + tx];
  __syncthreads();
#pragma unroll
  for (int rr = 0; rr < 4; ++rr)
    out[(long)(c0 + ty * 4 + rr) * R + r0 + tx] = (__bf16)t[tx][ty * 4 + rr];
}

// ============ GEMM: C = A[M,K] * Bt[N,K]^T + bias ============
// Tile 128x128, BK=64, 4 waves (2m x 2n), per-wave C = 64x64 (acc[4][4]).
// LDS: 2 buffers x 32 KB = 64 KB -> 2 blocks/CU (inter-block overlap).
// Per K-tile: stage next tile (8 gloads), VMCNT(8) counted, 2 barriers, 32 MFMA.
// Swizzle: byte-col ^= ((row&7)<<4) on gload source AND ds_read.
// MODE 0: scatter -> q[B,H,S,D] (pre-scaled 1/8), k[B,H,S,D], v^T[B,H,D,S]
// MODE 1: fp32 -> fo[M,N]
template <int MODE>
__launch_bounds__(256, 2)
__global__ void k_gemm2(const __bf16* __restrict__ A, const __bf16* __restrict__ Bt,
                        const float* __restrict__ bias, int M, int N, int K, int NBX,
                        __bf16* __restrict__ qo, __bf16* __restrict__ ko,
                        __bf16* __restrict__ vo, float* __restrict__ fo) {
  __shared__ __bf16 lds[2][2][8192];  // [buf][A/B][128 rows x 64 cols]
  const int tid = threadIdx.x;
  const int l = tid & 63, w = tid >> 6;          // 4 waves
  const int lm = l & 15, lq = l >> 4;
  const int wm = w >> 1, wn = w & 1;
  // XCD-affinity: xcd owns bn in [xcd*NBX, (xcd+1)*NBX)
  const int xcd = blockIdx.x & 7, s = blockIdx.x >> 3;
  const int bn = xcd * NBX + s % NBX;
  const int bm = s / NBX;
  const int nt = K >> 6;

  // staging: thread covers row (li*32 + tid>>3), 16B chunk (tid&7), pre-swizzled src
  const int rA = tid >> 3;
  const int scol = (((tid & 7) * 16) ^ ((rA & 7) << 4)) >> 1;  // elements
  long a_off[4], b_off[4];
#pragma unroll
  for (int li = 0; li < 4; ++li) {
    a_off[li] = (long)(bm * 128 + li * 32 + rA) * K + scol;
    b_off[li] = (long)(bn * 128 + li * 32 + rA) * K + scol;
  }
#define STAGE(buf, t) { \
    gload_lds16(A + a_off[0] + (long)(t) * 64, &lds[buf][0][tid * 8]); \
    gload_lds16(A + a_off[1] + (long)(t) * 64, &lds[buf][0][2048 + tid * 8]); \
    gload_lds16(A + a_off[2] + (long)(t) * 64, &lds[buf][0][4096 + tid * 8]); \
    gload_lds16(A + a_off[3] + (long)(t) * 64, &lds[buf][0][6144 + tid * 8]); \
    gload_lds16(Bt + b_off[0] + (long)(t) * 64, &lds[buf][1][tid * 8]); \
    gload_lds16(Bt + b_off[1] + (long)(t) * 64, &lds[buf][1][2048 + tid * 8]); \
    gload_lds16(Bt + b_off[2] + (long)(t) * 64, &lds[buf][1][4096 + tid * 8]); \
    gload_lds16(Bt + b_off[3] + (long)(t) * 64, &lds[buf][1][6144 + tid * 8]); }

  // fragment read offsets (element units; row stride 64 elems = 128 B)
  const int aswz = (lm & 7) << 4;
  const int cofs0 = ((0 * 64 + lq * 16) ^ aswz) >> 1;
  const int cofs1 = ((1 * 64 + lq * 16) ^ aswz) >> 1;
  const int arow = wm * 64 + lm;   // + mi*16
  const int brow = wn * 64 + lm;   // + ni*16

  f32x4 acc[4][4] = {};

  STAGE(0, 0);  // prologue: tile 0 in flight (8)

  for (int t = 0; t < nt; ++t) {
    const int cur = t & 1;
    if (t + 1 < nt) { STAGE(cur ^ 1, t + 1); VMCNT(8); }
    else VMCNT(0);
    BARRIER();
    const __bf16* La = lds[cur][0];
    const __bf16* Lbv = lds[cur][1];
    bf16x8 af[4][2], bfr[4][2];
#pragma unroll
    for (int mi = 0; mi < 4; ++mi) {
      af[mi][0] = *(const bf16x8*)&La[(arow + mi * 16) * 64 + cofs0];
      af[mi][1] = *(const bf16x8*)&La[(arow + mi * 16) * 64 + cofs1];
    }
#pragma unroll
    for (int ni = 0; ni < 4; ++ni) {
      bfr[ni][0] = *(const bf16x8*)&Lbv[(brow + ni * 16) * 64 + cofs0];
      bfr[ni][1] = *(const bf16x8*)&Lbv[(brow + ni * 16) * 64 + cofs1];
    }
    LGKM0(); SCHED0();
    __builtin_amdgcn_s_setprio(1);
#pragma unroll
    for (int ks = 0; ks < 2; ++ks)
#pragma unroll
      for (int mi = 0; mi < 4; ++mi)
#pragma unroll
        for (int ni = 0; ni < 4; ++ni)
          acc[mi][ni] = __builtin_amdgcn_mfma_f32_16x16x32_bf16(af[mi][ks], bfr[ni][ks],
                                                                acc[mi][ni], 0, 0, 0);
    __builtin_amdgcn_s_setprio(0);
    SCHED0();
    BARRIER();  // reads done before next iter's STAGE overwrites buf^1
  }

  if (MODE == 0) {
#pragma unroll
    for (int ni = 0; ni < 4; ++ni) {
      const int c = bn * 128 + wn * 64 + ni * 16 + lm;
      const float bv = bias[c];
      const int which = c >> 10, cc = c & 1023, hh = cc >> 6, d = cc & 63;
#pragma unroll
      for (int mi = 0; mi < 4; ++mi)
#pragma unroll
        for (int i = 0; i < 4; ++i) {
          const int r = bm * 128 + wm * 64 + mi * 16 + lq * 4 + i;
          const int b = r >> 10, s_ = r & 1023;
          float fv = acc[mi][ni][i] + bv;
          if (which == 0) fv *= 0.125f;  // fold 1/sqrt(D) into Q
          const __bf16 v = (__bf16)fv;
          const long hb = (long)(b * 16 + hh);
          if (which == 0)      qo[(hb * 1024 + s_) * 64 + d] = v;
          else if (which == 1) ko[(hb * 1024 + s_) * 64 + d] = v;
          else                 vo[(hb * 64 + d) * 1024 + s_] = v;
        }
    }
  } else {
#pragma unroll
    for (int ni = 0; ni < 4; ++ni) {
      const int c = bn * 128 + wn * 64 + ni * 16 + lm;
      const float bv = bias[c];
#pragma unroll
      for (int mi = 0; mi < 4; ++mi)
#pragma unroll
        for (int i = 0; i < 4; ++i) {
          const int r = bm * 128 + wm * 64 + mi * 16 + lq * 4 + i;
          fo[(long)r * N + c] = acc[mi][ni][i] + bv;
        }
    }
  }
#undef STAGE
}

// -------- causal flash attention, KVBLK=64, swapped-QK^T, no LDS --------
// Per iter: 2 independent QK chains (8 MFMA, ILP), ONE softmax/rescale/pack
// pass over 64 keys, 8 PV MFMA.
__device__ __forceinline__ void attn_qtile(const __bf16* __restrict__ Q,
                                           const __bf16* __restrict__ Kh,
                                           const __bf16* __restrict__ Vt,
                                           __bf16* __restrict__ ob,
                                           int b, int h, int qbw, int l) {
  const int lm = l & 31, hi = l >> 5;

  bf16x8 qf[4];
#pragma unroll
  for (int ds = 0; ds < 4; ++ds)
    qf[ds] = *(const bf16x8*)(Q + (long)(qbw + lm) * 64 + ds * 16 + hi * 8);

  f32x16 oacc0 = {}, oacc1 = {};
  float m = -__builtin_inff(), s = 0.f;

  const int nt64 = (qbw >> 6) + 1;  // 64-key blocks; last may be part-masked
  for (int kt = 0; kt < nt64; ++kt) {
    const int k0 = kt * 64;
    f32x16 st0 = {}, st1 = {};
#pragma unroll
    for (int ds = 0; ds < 4; ++ds) {
      bf16x8 kf0 = *(const bf16x8*)(Kh + (long)(k0 + lm) * 64 + ds * 16 + hi * 8);
      bf16x8 kf1 = *(const bf16x8*)(Kh + (long)(k0 + 32 + lm) * 64 + ds * 16 + hi * 8);
      st0 = __builtin_amdgcn_mfma_f32_32x32x16_bf16(kf0, qf[ds], st0, 0, 0, 0);
      st1 = __builtin_amdgcn_mfma_f32_32x32x16_bf16(kf1, qf[ds], st1, 0, 0, 0);
    }
    if (kt == nt64 - 1) {  // diagonal / tail masking
      const int q = qbw + lm;
#pragma unroll
      for (int r = 0; r < 16; ++r) {
        const int key = k0 + (r & 3) + 8 * (r >> 2) + 4 * hi;
        if (key > q)      st0[r] = -__builtin_inff();
        if (key + 32 > q) st1[r] = -__builtin_inff();
      }
    }
    float tm = fmaxf(st0[0], st1[0]);
#pragma unroll
    for (int r = 1; r < 16; ++r) tm = fmaxf(tm, fmaxf(st0[r], st1[r]));
    tm = fmaxf(tm, __shfl_xor(tm, 32));
    if (!__all(tm <= m + 8.f)) {   // defer-max
      const float mn = fmaxf(m, tm);
      const float fac = __expf(m - mn);
      m = mn;
      s *= fac;
#pragma unroll
      for (int r = 0; r < 16; ++r) {
        const int qr = (r & 3) + 8 * (r >> 2) + 4 * hi;
        const float fr = __int_as_float(
            __builtin_amdgcn_ds_bpermute(qr * 4, __float_as_int(fac)));
        oacc0[r] *= fr; oacc1[r] *= fr;
      }
    }
    float ts = 0.f;
    unsigned int w8a[8], w8b[8];
#pragma unroll
    for (int t = 0; t < 8; ++t) {
      const float pa_ = __expf(st0[2 * t] - m), pb_ = __expf(st0[2 * t + 1] - m);
      ts += pa_ + pb_;
      union { __bf16 hh[2]; unsigned int u; } pk;
      pk.hh[0] = (__bf16)pa_; pk.hh[1] = (__bf16)pb_;
      w8a[t] = pk.u;
    }
#pragma unroll
    for (int t = 0; t < 8; ++t) {
      const float pa_ = __expf(st1[2 * t] - m), pb_ = __expf(st1[2 * t + 1] - m);
      ts += pa_ + pb_;
      union { __bf16 hh[2]; unsigned int u; } pk;
      pk.hh[0] = (__bf16)pa_; pk.hh[1] = (__bf16)pb_;
      w8b[t] = pk.u;
    }
    ts += __shfl_xor(ts, 32);
    s += ts;
    // build 4 PV A-frags: pa0/pa1 from w8a (keys k0+0..31), pa2/pa3 from w8b
    union { unsigned int wd[4]; bf16x8 v; } pa[4];
    {
      const unsigned int e0 = __shfl_xor(hi ? w8a[0] : w8a[2], 32);
      const unsigned int e1 = __shfl_xor(hi ? w8a[1] : w8a[3], 32);
      const unsigned int e2 = __shfl_xor(hi ? w8a[4] : w8a[6], 32);
      const unsigned int e3 = __shfl_xor(hi ? w8a[5] : w8a[7], 32);
      if (hi) {
        pa[0].wd[0] = e0;     pa[0].wd[1] = e1;     pa[0].wd[2] = w8a[2]; pa[0].wd[3] = w8a[3];
        pa[1].wd[0] = e2;     pa[1].wd[1] = e3;     pa[1].wd[2] = w8a[6]; pa[1].wd[3] = w8a[7];
      } else {
        pa[0].wd[0] = w8a[0]; pa[0].wd[1] = w8a[1]; pa[0].wd[2] = e0;     pa[0].wd[3] = e1;
        pa[1].wd[0] = w8a[4]; pa[1].wd[1] = w8a[5]; pa[1].wd[2] = e2;     pa[1].wd[3] = e3;
      }
    }
    {
      const unsigned int e0 = __shfl_xor(hi ? w8b[0] : w8b[2], 32);
      const unsigned int e1 = __shfl_xor(hi ? w8b[1] : w8b[3], 32);
      const unsigned int e2 = __shfl_xor(hi ? w8b[4] : w8b[6], 32);
      const unsigned int e3 = __shfl_xor(hi ? w8b[5] : w8b[7], 32);
      if (hi) {
        pa[2].wd[0] = e0;     pa[2].wd[1] = e1;     pa[2].wd[2] = w8b[2]; pa[2].wd[3] = w8b[3];
        pa[3].wd[0] = e2;     pa[3].wd[1] = e3;     pa[3].wd[2] = w8b[6]; pa[3].wd[3] = w8b[7];
      } else {
        pa[2].wd[0] = w8b[0]; pa[2].wd[1] = w8b[1]; pa[2].wd[2] = e0;     pa[2].wd[3] = e1;
        pa[3].wd[0] = w8b[4]; pa[3].wd[1] = w8b[5]; pa[3].wd[2] = e2;     pa[3].wd[3] = e3;
      }
    }
#pragma unroll
    for (int t = 0; t < 4; ++t) {
      bf16x8 vf0 = *(const bf16x8*)(Vt + (long)lm * 1024 + k0 + t * 16 + hi * 8);
      bf16x8 vf1 = *(const bf16x8*)(Vt + (long)(32 + lm) * 1024 + k0 + t * 16 + hi * 8);
      oacc0 = __builtin_amdgcn_mfma_f32_32x32x16_bf16(pa[t].v, vf0, oacc0, 0, 0, 0);
      oacc1 = __builtin_amdgcn_mfma_f32_32x32x16_bf16(pa[t].v, vf1, oacc1, 0, 0, 0);
    }
  }
  const float invs = 1.f / s;
#pragma unroll
  for (int r = 0; r < 16; ++r) {
    const int qr = (r & 3) + 8 * (r >> 2) + 4 * hi;
    const float inv = __int_as_float(
        __builtin_amdgcn_ds_bpermute(qr * 4, __float_as_int(invs)));
    const long row = (long)(b * 1024 + qbw + qr) * 1024 + h * 64;
    ob[row + lm]      = (__bf16)(oacc0[r] * inv);
    ob[row + 32 + lm] = (__bf16)(oacc1[r] * inv);
  }
}

// 512 blocks, XCD-affinity: the 4 blocks of one (b,h) land on one XCD.
// launch_bounds(256,2): min 2 waves/EU -> VGPR cap 256, kills the 64-VGPR
// default cap that was spilling ~12 MB of scratch per call (R7 profile).
__global__ __launch_bounds__(256, 2)
void k_attn(const __bf16* __restrict__ qb_, const __bf16* __restrict__ kb,
            const __bf16* __restrict__ vtb, __bf16* __restrict__ ob) {
  const int l = threadIdx.x & 63, w = threadIdx.x >> 6;
  const int bid = blockIdx.x;
  const int xcd = bid & 7, slot = bid >> 3;
  const int bh = xcd + 8 * (slot >> 2);
  const int j = slot & 3;
  const int wi = j * 4 + w;                      // 0..15
  const int b = bh >> 4, h = bh & 15;
  const __bf16* Q  = qb_ + (long)bh * 65536;
  const __bf16* Kh = kb  + (long)bh * 65536;
  const __bf16* Vt = vtb + (long)bh * 65536;
  attn_qtile(Q, Kh, Vt, ob, b, h, wi * 32, l);         // wi & 31-wi have opposite
  attn_qtile(Q, Kh, Vt, ob, b, h, (31 - wi) * 32, l);  // parity: balanced waste
}

extern "C" void kernel_launch(void* const* d_in, const int* in_sizes, int n_in,
                              void* d_out, int out_size, void* d_ws, size_t ws_size,
                              hipStream_t stream) {
  const float* x      = (const float*)d_in[0];
  const float* w_attn = (const float*)d_in[1];
  const float* b_attn = (const float*)d_in[2];
  const float* w_proj = (const float*)d_in[3];
  const float* b_proj = (const float*)d_in[4];
  float* out = (float*)d_out;

  char* ws = (char*)d_ws;
  const size_t SZ_XBF = (size_t)8192 * 1024 * 2;   // 16.8 MB
  __bf16* x_bf = (__bf16*)ws;  ws += SZ_XBF;
  __bf16* wat  = (__bf16*)ws;  ws += (size_t)3072 * 1024 * 2;
  __bf16* wpt  = (__bf16*)ws;  ws += (size_t)1024 * 1024 * 2;
  __bf16* qb   = (__bf16*)ws;  ws += SZ_XBF;       // [B,H,S,D], pre-scaled 1/8
  __bf16* kb   = (__bf16*)ws;  ws += SZ_XBF;       // [B,H,S,D]
  __bf16* vtb  = (__bf16*)ws;  ws += SZ_XBF;       // [B,H,D,S]
  __bf16* obf  = (__bf16*)ws;  ws += SZ_XBF;       // [B,S,NX]

  k_cast<<<8192, 256, 0, stream>>>(x, x_bf, 2097152);
  k_transpose_cast<<<dim3(96, 32), 256, 0, stream>>>(w_attn, wat, 1024, 3072);
  k_transpose_cast<<<dim3(32, 32), 256, 0, stream>>>(w_proj, wpt, 1024, 1024);
  // QKV: M=8192 (64 bm) x N=3072 (24 bn) -> 1536 blocks; NBX = 24/8 = 3
  k_gemm2<0><<<1536, 256, 0, stream>>>(x_bf, wat, b_attn, 8192, 3072, 1024, 3,
                                       qb, kb, vtb, nullptr);
  k_attn<<<512, 256, 0, stream>>>(qb, kb, vtb, obf);
  // proj: 64 bm x 8 bn -> 512 blocks; NBX = 1
  k_gemm2<1><<<512, 256, 0, stream>>>(obf, wpt, b_proj, 8192, 1024, 1024, 1,
                                      nullptr, nullptr, nullptr, out);
}